// Round 6
// baseline (2174.801 us; speedup 1.0000x reference)
//
#include <hip/hip_runtime.h>
#include <cmath>

#define T_LEN 512
#define BS    64
#define F_DIM 128
#define HSZ   256
#define DA    64
#define RH    8

// output offsets (floats)
#define OFF_HT   8388608
#define OFF_CT   8404992
#define OFF_ATT  8421376

// ---------------- K1: scores = tanh(x@W1^T + b1)@W2^T + b2 ----------------
__global__ __launch_bounds__(256) void k_scores(
    const float* __restrict__ x, const float* __restrict__ w1,
    const float* __restrict__ b1, const float* __restrict__ w2,
    const float* __restrict__ b2, float* __restrict__ scores)
{
  __shared__ float wl[DA * 129];   // padded stride 129 -> conflict-free
  __shared__ float xs[4][F_DIM];
  __shared__ float hid[4][DA];
  int tid = threadIdx.x;
  for (int id = tid; id < DA * F_DIM; id += 256) {
    int a = id >> 7, f = id & 127;
    wl[a * 129 + f] = w1[id];
  }
  int wv = tid >> 6, lane = tid & 63;
  int pair = blockIdx.x * 4 + wv;          // pair = b*512 + t
  const float* xr = x + (size_t)pair * F_DIM;
  xs[wv][lane]      = xr[lane];
  xs[wv][64 + lane] = xr[64 + lane];
  __syncthreads();
  float acc = b1[lane];
  #pragma unroll 8
  for (int f = 0; f < F_DIM; ++f)
    acc += xs[wv][f] * wl[lane * 129 + f];
  hid[wv][lane] = tanhf(acc);
  __syncthreads();
  if (lane < RH) {
    float sc = b2[lane];
    #pragma unroll 8
    for (int a = 0; a < DA; ++a)
      sc += hid[wv][a] * w2[lane * DA + a];
    scores[(size_t)pair * RH + lane] = sc;
  }
}

// ------- K2: softmax prefix sums -> M (4 t-chunks per batch), attn output -------
__global__ __launch_bounds__(512) void k_attn_M(
    const float* __restrict__ x, const float* __restrict__ scores,
    float* __restrict__ M, float* __restrict__ out)
{
  __shared__ float se[T_LEN * 9];
  __shared__ float ivd[T_LEN * 9];
  __shared__ float segsum[RH][65];
  __shared__ float cp[4 * F_DIM * RH];
  __shared__ float gmax[RH];
  int tid = threadIdx.x;
  int blk = blockIdx.x;
  int j = blk >> 6, b = blk & 63;
  int p0 = j * 128, e = p0 + 128;
  int e8 = e * 8;
  const float* sb = scores + (size_t)b * T_LEN * RH;
  for (int id = tid; id < e8; id += 512)
    se[(id >> 3) * 9 + (id & 7)] = sb[id];
  __syncthreads();
  {  // per-r max over [0,e)
    int w = tid >> 6, l = tid & 63;
    float m = -INFINITY;
    for (int t = l; t < e; t += 64)
      m = fmaxf(m, se[t * 9 + w]);
    #pragma unroll
    for (int off = 32; off; off >>= 1)
      m = fmaxf(m, __shfl_xor(m, off));
    if (l == 0) gmax[w] = m;
  }
  __syncthreads();
  for (int id = tid; id < e8; id += 512) {
    int t = id >> 3, r = id & 7;
    se[t * 9 + r] = expf(se[t * 9 + r] - gmax[r]);
  }
  __syncthreads();
  int nseg = e >> 3;
  {
    int r = tid >> 6, seg = tid & 63;
    if (seg < nseg) {
      float run = 0.f;
      #pragma unroll
      for (int i = 0; i < 8; ++i) {
        int t = seg * 8 + i;
        run += se[t * 9 + r];
        ivd[t * 9 + r] = run;
      }
      segsum[r][seg] = run;
    }
  }
  __syncthreads();
  if (tid < RH) {   // exclusive scan of segment sums
    float off = 0.f;
    for (int sg = 0; sg < nseg; ++sg) {
      float tmp = segsum[tid][sg];
      segsum[tid][sg] = off;
      off += tmp;
    }
  }
  __syncthreads();
  for (int id = tid; id < e8; id += 512) {
    int t = id >> 3, r = id & 7;
    ivd[t * 9 + r] = 1.f / (ivd[t * 9 + r] + segsum[r][t >> 3]);
  }
  __syncthreads();
  if (j == 3) {  // attention output (full window), layout [b][r][t]
    for (int id = tid; id < T_LEN * RH; id += 512) {
      int r = id >> 9, t = id & 511;
      out[OFF_ATT + ((size_t)b * RH + r) * T_LEN + t] =
          se[t * 9 + r] * ivd[511 * 9 + r];
    }
  }
  const float* xb = x + (size_t)b * T_LEN * F_DIM;
  {
    int q = tid >> 7, f = tid & 127;
    int len = p0 >> 2;
    int t0 = q * len, t1 = t0 + len;
    float pp[RH];
    #pragma unroll
    for (int r = 0; r < RH; ++r) pp[r] = 0.f;
    for (int t = t0; t < t1; ++t) {
      float xv = xb[t * F_DIM + f];
      #pragma unroll
      for (int r = 0; r < RH; ++r) pp[r] += se[t * 9 + r] * xv;
    }
    float* c = &cp[(q * F_DIM + f) * RH];
    #pragma unroll
    for (int r = 0; r < RH; ++r) c[r] = pp[r];
  }
  __syncthreads();
  if (tid < F_DIM) {
    int f = tid;
    float num[RH];
    #pragma unroll
    for (int r = 0; r < RH; ++r) num[r] = 0.f;
    #pragma unroll
    for (int q = 0; q < 4; ++q) {
      const float* c = &cp[(q * F_DIM + f) * RH];
      #pragma unroll
      for (int r = 0; r < RH; ++r) num[r] += c[r];
    }
    float* Mb = M + (size_t)b * T_LEN * F_DIM;
    for (int t = p0; t < e; ++t) {
      float xv = xb[t * F_DIM + f];
      float acc = 0.f;
      #pragma unroll
      for (int r = 0; r < RH; ++r) {
        num[r] += se[t * 9 + r] * xv;
        acc += num[r] * ivd[t * 9 + r];
      }
      Mb[t * F_DIM + f] = 0.125f * acc;
    }
  }
}

// ------------- K3: 4-batch round-robin recurrence, RTT hidden across batches -------------
// 256 blocks = 16 slices (sl: 16 hs each) x 16 batch-quads (bq: batches 4bq..4bq+3).
// 1024 threads = 16 kq-waves x 64 cols; col = hs*4 + type; w[24] per thread (NO spill).
// Per iteration t: 4 segments; segment q = { gemv_q (LDS-broadcast, 24 FMA) ->
// part store; pollers fetch NEXT segment's partner h; bar; butterfly reduce ->
// 16 parallel cell updates -> publish tagged u64; bar }. Publish->poll gap = 3
// segments, hiding the fabric RTT. Roles vmcnt-disjoint (R4/R5 lessons):
// pollers (256..495) never store/load; stagers (896..1023) issue their single
// float4 M-load at seg0 start (drain hides under poll); cell threads never poll.
__global__ __launch_bounds__(1024, 4) void k_lstm(
    const float* __restrict__ M, const float* __restrict__ Wi,
    const float* __restrict__ Wh, const float* __restrict__ bias,
    unsigned long long* __restrict__ slab64,
    float* __restrict__ out)
{
  __shared__ float u[4][2][384];   // [batch][parity][ M(128) | h(256) ]
  __shared__ float part[1024];     // [kq][col]
  int tid = threadIdx.x;
  int blk = blockIdx.x;
  int sl = blk >> 4;               // slice 0..15
  int bq = blk & 15;               // batch quad
  int b0 = bq * 4;
  int kq = tid >> 6;               // wave id = K chunk
  int col = tid & 63;
  int hs = col >> 2, type = col & 3;
  int gcol = type * 256 + sl * 16 + hs;

  // 24 weights per thread: rows [24kq, 24kq+24) of [Wi(128); Wh(256)], col gcol
  float w[24];
  #pragma unroll
  for (int i = 0; i < 24; ++i) {
    int kk = kq * 24 + i;
    w[i] = (kk < F_DIM) ? Wi[(size_t)kk * 1024 + gcol]
                        : Wh[(size_t)(kk - F_DIM) * 1024 + gcol];
  }
  float bsum = (kq == 0) ? bias[gcol] : 0.f;
  const float* Mb = M + (size_t)b0 * T_LEN * F_DIM;

  // prologue: zero h-part parity 0; stage M[q][0]
  { int q = tid >> 8, idx = tid & 255; u[q][0][128 + idx] = 0.f; }
  if (tid >= 512) {
    int r = tid - 512, q = r >> 7, f = r & 127;
    u[q][0][f] = Mb[((size_t)q * T_LEN) * F_DIM + f];
  }
  __syncthreads();

  float cc0 = 0.f, cc1 = 0.f, cc2 = 0.f, cc3 = 0.f;
  float4 mreg = {0.f, 0.f, 0.f, 0.f};

#define SEG(Q, CREG) do { \
    int par = t & 1; \
    if (Q == 0 && tid >= 896) {  /* stagers: issue M[*][t+1] loads early */ \
      int rr = tid - 896, qs = rr >> 5, f4 = rr & 31; \
      int ts = (t + 1 < T_LEN) ? t + 1 : 0; \
      mreg = *(const float4*)&Mb[((size_t)qs * T_LEN + ts) * F_DIM + f4 * 4]; \
    } \
    { /* gemv: wave-uniform LDS broadcasts, 24 FMA */ \
      const float* uq = &u[Q][par][kq * 24]; \
      float acc = bsum; \
      _Pragma("unroll") \
      for (int i = 0; i < 24; ++i) acc += uq[i] * w[i]; \
      part[tid] = acc; \
    } \
    if (tid >= 256 && tid < 496) {  /* pollers: clean vmcnt, 1 word each */ \
      int rr = tid - 256, p = rr >> 4, phs = rr & 15; \
      int sp = p + (p >= sl); \
      int Qn = (Q + 1) & 3; \
      int tau = (Q == 3) ? t + 1 : t; \
      if (tau >= 1 && tau < T_LEN) { \
        const unsigned long long* ad = \
            &slab64[(size_t)(tau & 1) * 16384 + (size_t)(b0 + Qn) * 256 + sp * 16 + phs]; \
        unsigned long long got; \
        do { got = __hip_atomic_load(ad, __ATOMIC_RELAXED, __HIP_MEMORY_SCOPE_AGENT); } \
        while ((unsigned)(got >> 32) != (unsigned)tau); \
        u[Qn][tau & 1][128 + sp * 16 + phs] = __uint_as_float((unsigned)got); \
      } \
    } \
    __syncthreads(); \
    if (tid < 256) {  /* butterfly reduce + 16 parallel cells */ \
      int colr = tid >> 2, s4 = tid & 3; \
      float tot = part[(4 * s4 + 0) * 64 + colr] + part[(4 * s4 + 1) * 64 + colr] \
                + part[(4 * s4 + 2) * 64 + colr] + part[(4 * s4 + 3) * 64 + colr]; \
      tot += __shfl_xor(tot, 1); \
      tot += __shfl_xor(tot, 2); \
      int lane = tid & 63; \
      float gF = __shfl(tot, (lane + 4) & 63); \
      float gG = __shfl(tot, (lane + 8) & 63); \
      float gO = __shfl(tot, (lane + 12) & 63); \
      if ((tid & 15) == 0) { \
        int h = tid >> 4; \
        float ii = 1.f / (1.f + __expf(-tot)); \
        float ff = 1.f / (1.f + __expf(-gF)); \
        float gg = 1.f - 2.f / (__expf(2.f * gG) + 1.f); \
        float oo = 1.f / (1.f + __expf(-gO)); \
        CREG = ff * CREG + ii * gg; \
        float tc = 1.f - 2.f / (__expf(2.f * CREG) + 1.f); \
        float hv = oo * tc; \
        u[Q][par ^ 1][128 + sl * 16 + h] = hv; \
        unsigned long long pk = ((unsigned long long)(unsigned)(t + 1) << 32) \
                              | (unsigned long long)__float_as_uint(hv); \
        __hip_atomic_store(&slab64[(size_t)(par ^ 1) * 16384 + (size_t)(b0 + Q) * 256 + sl * 16 + h], \
                           pk, __ATOMIC_RELAXED, __HIP_MEMORY_SCOPE_AGENT); \
        out[((size_t)(b0 + Q) * T_LEN + t) * HSZ + sl * 16 + h] = hv; \
        if (t == T_LEN - 1) { \
          out[OFF_HT + (b0 + Q) * HSZ + sl * 16 + h] = hv; \
          out[OFF_CT + (b0 + Q) * HSZ + sl * 16 + h] = CREG; \
        } \
      } \
    } \
    if (Q == 1 && tid >= 896) {  /* stagers: write staged M[t+1] row */ \
      int rr = tid - 896, qs = rr >> 5, f4 = rr & 31; \
      if (t + 1 < T_LEN) *(float4*)&u[qs][(t + 1) & 1][f4 * 4] = mreg; \
    } \
    __syncthreads(); \
  } while (0)

  for (int t = 0; t < T_LEN; ++t) {
    SEG(0, cc0);
    SEG(1, cc1);
    SEG(2, cc2);
    SEG(3, cc3);
  }
#undef SEG
}

extern "C" void kernel_launch(void* const* d_in, const int* in_sizes, int n_in,
                              void* d_out, int out_size, void* d_ws, size_t ws_size,
                              hipStream_t stream) {
  const float* x   = (const float*)d_in[0];
  const float* w1  = (const float*)d_in[1];
  const float* b1  = (const float*)d_in[2];
  const float* w2  = (const float*)d_in[3];
  const float* b2  = (const float*)d_in[4];
  const float* Wi  = (const float*)d_in[5];
  const float* Wh  = (const float*)d_in[6];
  const float* bia = (const float*)d_in[7];
  float* out = (float*)d_out;
  float* ws  = (float*)d_ws;

  float* scores = ws;                                    // 262144 f
  float* M      = ws + 262144;                           // 4194304 f
  unsigned long long* slab64 =
      (unsigned long long*)(ws + 262144 + 4194304);      // 2*64*256 u64

  hipLaunchKernelGGL(k_scores, dim3(8192), dim3(256), 0, stream,
                     x, w1, b1, w2, b2, scores);
  hipLaunchKernelGGL(k_attn_M, dim3(256), dim3(512), 0, stream,
                     x, scores, M, out);
  hipLaunchKernelGGL(k_lstm, dim3(256), dim3(1024), 0, stream,
                     M, Wi, Wh, bia, slab64, out);
}